// Round 6
// baseline (17.718 us; speedup 1.0000x reference)
//
#include <hip/hip_runtime.h>

// FlashRecoModel: out[b,p,t] = sum_f pe[b,f,p]*conf[b,f] * w[b,f,t]
// w = Gaussian(center=clip(time*T,0,T-1), sigma) normalized over ticks.
//
// R6 = R5 with the nontemporal-store type fixed (clang ext_vector_type(4)
// instead of HIP_vector_type float4 — the builtin rejects struct types).
//
// Structure (proven best, R2-derived): TT=32, 512 blocks, LDS transpose,
// block-coalesced full-line writes; plus:
//  - predicated 8-deep pe prefetch issued before the exp phase
//  - theta-identity denominator: sum_t exp(-(t-tb)^2/2s^2) =
//      s*sqrt(2pi)*(1 + 2*exp(-2pi^2 s^2)*cos(2pi*tb))  (~1e-12 rel for
//    s>=0.6 away from boundaries); serial-sum fallback for boundary flashes.
//  - no lo/len in the hot path (exp underflow masks the window)
//  - nontemporal output stores (streaming, no reuse)

#define F       128
#define TT      32     // ticks per tile
#define BLOCK   256    // == P
#define MAXSLOT 128    // worst case: all flashes hit one tile
#define CHUNK   8      // prefetch depth (E[count]~3)

typedef float fvec4 __attribute__((ext_vector_type(4)));

__global__ __launch_bounds__(BLOCK) void flash_reco_tile(
    const float* __restrict__ pe,      // [B, F, P]
    const float* __restrict__ ftime,   // [B, F]
    const float* __restrict__ fconf,   // [B, F]
    const float* __restrict__ sig_p,   // scalar
    float* __restrict__ out,           // [B, P, T]
    int P, int T, int ntiles)
{
    __shared__ int   wcnt[2];
    __shared__ int   fl_f [MAXSLOT];
    __shared__ float fl_tb[MAXSLOT];
    __shared__ float fl_sc[MAXSLOT];          // conf / denom
    __shared__ float wt [MAXSLOT * TT];       // 16 KB tile weights (unnorm.)
    __shared__ float stg[BLOCK * (TT + 1)];   // 33 KB transpose staging

    const int tid  = threadIdx.x;
    const int b    = blockIdx.x / ntiles;
    const int tile = blockIdx.x % ntiles;
    const int t0   = tile * TT;
    const float sigma   = *sig_p;
    const float inv_sig = 1.0f / sigma;
    const float r       = 8.0f * sigma;

    // ---- phase 1: active flashes + scale (conf/denominator) ----
    bool act = false;
    float tb = 0.f, sc = 0.f;
    if (tid < F) {
        const float tm = ftime[b * F + tid];
        const float cf = fconf[b * F + tid];
        tb = fminf(fmaxf(tm * (float)T, 0.0f), (float)(T - 1));
        act = (tb + r >= (float)t0) && (tb - r <= (float)(t0 + TT - 1));
        if (act) {
            float denom;
            if (sigma >= 0.6f && tb - r > 0.0f && tb + r < (float)(T - 1)) {
                // full-lattice Gaussian sum via theta identity
                const float q  = __expf(-19.7392088f * sigma * sigma);
                const float fr = tb - truncf(tb);
                denom = sigma * 2.50662827f
                      * (1.0f + 2.0f * q * __cosf(6.28318531f * fr));
            } else {
                int lo = (int)ceilf(tb - r);   if (lo < 0) lo = 0;
                int hi = (int)floorf(tb + r);  if (hi > T - 1) hi = T - 1;
                float s = 0.0f;
                for (int k = lo; k <= hi; ++k) {
                    const float z = ((float)k - tb) * inv_sig;
                    s += __expf(-0.5f * z * z);
                }
                denom = s;
            }
            sc = cf / (denom + 1e-10f);
        }
    }
    // deterministic compaction (flashes live in waves 0,1 only)
    const unsigned long long m = __ballot(act);
    const int lane = tid & 63, wv = tid >> 6;
    if (wv < 2 && lane == 0) wcnt[wv] = __popcll(m);
    __syncthreads();
    const int count = wcnt[0] + wcnt[1];
    if (act) {
        const int slot = __popcll(m & ((1ULL << lane) - 1ULL))
                       + (wv == 1 ? wcnt[0] : 0);
        fl_f[slot]  = tid;
        fl_tb[slot] = tb;
        fl_sc[slot] = sc;
    }
    __syncthreads();

    // ---- phase 2-pre: issue pe prefetch (hides HBM under exp phase) ----
    float sv[CHUNK];
    #pragma unroll
    for (int u = 0; u < CHUNK; ++u)
        sv[u] = (u < count) ? pe[((long)b * F + fl_f[u]) * P + tid] : 0.0f;

    // ---- phase 2: unnormalized tile weights (underflow masks the window) ----
    for (int idx = tid; idx < count * TT; idx += BLOCK) {
        const int a = idx >> 5, j = idx & (TT - 1);
        const float z = ((float)(t0 + j) - fl_tb[a]) * inv_sig;
        wt[idx] = __expf(-0.5f * z * z);
    }
    __syncthreads();

    // ---- phase 3: per-thread (p = tid) register accumulation ----
    float acc[TT];
    #pragma unroll
    for (int j = 0; j < TT; ++j) acc[j] = 0.0f;

    #pragma unroll
    for (int a = 0; a < CHUNK; ++a) {
        if (a < count) {
            const float s = sv[a] * fl_sc[a];
            const float4* w4 = (const float4*)&wt[a * TT];  // uniform -> bcast
            #pragma unroll
            for (int q = 0; q < TT / 4; ++q) {
                const float4 w = w4[q];
                acc[q*4+0] += s * w.x;
                acc[q*4+1] += s * w.y;
                acc[q*4+2] += s * w.z;
                acc[q*4+3] += s * w.w;
            }
        }
    }
    for (int a = CHUNK; a < count; ++a) {    // rare tail
        const float s = pe[((long)b * F + fl_f[a]) * P + tid] * fl_sc[a];
        const float4* w4 = (const float4*)&wt[a * TT];
        #pragma unroll
        for (int q = 0; q < TT / 4; ++q) {
            const float4 w = w4[q];
            acc[q*4+0] += s * w.x;
            acc[q*4+1] += s * w.y;
            acc[q*4+2] += s * w.z;
            acc[q*4+3] += s * w.w;
        }
    }

    // ---- phase 4: padded-LDS transpose, block-coalesced full-line writes ----
    #pragma unroll
    for (int j = 0; j < TT; ++j)
        stg[tid * (TT + 1) + j] = acc[j];    // bank (tid+j)%32: 2-way, free
    __syncthreads();

    const long rowbase = (long)b * P * T + t0;
    #pragma unroll
    for (int g = 0; g < BLOCK / 32; ++g) {
        const int p  = g * 32 + (tid >> 3);
        const int j4 = (tid & 7) * 4;
        fvec4 v;
        v.x = stg[p * (TT + 1) + j4 + 0];
        v.y = stg[p * (TT + 1) + j4 + 1];
        v.z = stg[p * (TT + 1) + j4 + 2];
        v.w = stg[p * (TT + 1) + j4 + 3];
        __builtin_nontemporal_store(v, (fvec4*)(out + rowbase + (long)p * T + j4));
    }
}

extern "C" void kernel_launch(void* const* d_in, const int* in_sizes, int n_in,
                              void* d_out, int out_size, void* d_ws, size_t ws_size,
                              hipStream_t stream) {
    const float* pe    = (const float*)d_in[0];  // [B,F,P]
    const float* ftime = (const float*)d_in[1];  // [B,F,1]
    const float* fconf = (const float*)d_in[2];  // [B,F,1]
    const float* sigma = (const float*)d_in[4];  // scalar

    const int BF = in_sizes[1];            // B*F = 1024
    const int P  = in_sizes[0] / BF;       // 256
    const int B  = BF / F;                 // 8
    const int T  = out_size / (B * P);     // 2048
    const int ntiles = (T + TT - 1) / TT;  // 64

    flash_reco_tile<<<dim3(B * ntiles), dim3(BLOCK), 0, stream>>>(
        pe, ftime, fconf, sigma, (float*)d_out, P, T, ntiles);
}

// Round 7
// 11.227 us; speedup vs baseline: 1.5782x; 1.5782x over previous
//
#include <hip/hip_runtime.h>

// FlashRecoModel: out[b,p,t] = sum_f pe[b,f,p]*conf[b,f] * w[b,f,t]
// w = Gaussian(center=clip(time*T,0,T-1), sigma) normalized over ticks.
//
// R7 = R6 with PLAIN stores (single-variable test: nontemporal-store
// regression hypothesis). Everything else identical to R6:
//  - TT=32, 512 blocks, LDS transpose, block-coalesced full-line writes
//  - predicated 8-deep pe prefetch issued before the exp phase
//  - theta-identity denominator (serial-sum fallback at boundaries)
//  - exp underflow masks the window (no lo/len in hot path)

#define F       128
#define TT      32     // ticks per tile
#define BLOCK   256    // == P
#define MAXSLOT 128    // worst case: all flashes hit one tile
#define CHUNK   8      // prefetch depth (E[count]~3)

__global__ __launch_bounds__(BLOCK) void flash_reco_tile(
    const float* __restrict__ pe,      // [B, F, P]
    const float* __restrict__ ftime,   // [B, F]
    const float* __restrict__ fconf,   // [B, F]
    const float* __restrict__ sig_p,   // scalar
    float* __restrict__ out,           // [B, P, T]
    int P, int T, int ntiles)
{
    __shared__ int   wcnt[2];
    __shared__ int   fl_f [MAXSLOT];
    __shared__ float fl_tb[MAXSLOT];
    __shared__ float fl_sc[MAXSLOT];          // conf / denom
    __shared__ float wt [MAXSLOT * TT];       // 16 KB tile weights (unnorm.)
    __shared__ float stg[BLOCK * (TT + 1)];   // 33 KB transpose staging

    const int tid  = threadIdx.x;
    const int b    = blockIdx.x / ntiles;
    const int tile = blockIdx.x % ntiles;
    const int t0   = tile * TT;
    const float sigma   = *sig_p;
    const float inv_sig = 1.0f / sigma;
    const float r       = 8.0f * sigma;

    // ---- phase 1: active flashes + scale (conf/denominator) ----
    bool act = false;
    float tb = 0.f, sc = 0.f;
    if (tid < F) {
        const float tm = ftime[b * F + tid];
        const float cf = fconf[b * F + tid];
        tb = fminf(fmaxf(tm * (float)T, 0.0f), (float)(T - 1));
        act = (tb + r >= (float)t0) && (tb - r <= (float)(t0 + TT - 1));
        if (act) {
            float denom;
            if (sigma >= 0.6f && tb - r > 0.0f && tb + r < (float)(T - 1)) {
                // full-lattice Gaussian sum via theta identity
                const float q  = __expf(-19.7392088f * sigma * sigma);
                const float fr = tb - truncf(tb);
                denom = sigma * 2.50662827f
                      * (1.0f + 2.0f * q * __cosf(6.28318531f * fr));
            } else {
                int lo = (int)ceilf(tb - r);   if (lo < 0) lo = 0;
                int hi = (int)floorf(tb + r);  if (hi > T - 1) hi = T - 1;
                float s = 0.0f;
                for (int k = lo; k <= hi; ++k) {
                    const float z = ((float)k - tb) * inv_sig;
                    s += __expf(-0.5f * z * z);
                }
                denom = s;
            }
            sc = cf / (denom + 1e-10f);
        }
    }
    // deterministic compaction (flashes live in waves 0,1 only)
    const unsigned long long m = __ballot(act);
    const int lane = tid & 63, wv = tid >> 6;
    if (wv < 2 && lane == 0) wcnt[wv] = __popcll(m);
    __syncthreads();
    const int count = wcnt[0] + wcnt[1];
    if (act) {
        const int slot = __popcll(m & ((1ULL << lane) - 1ULL))
                       + (wv == 1 ? wcnt[0] : 0);
        fl_f[slot]  = tid;
        fl_tb[slot] = tb;
        fl_sc[slot] = sc;
    }
    __syncthreads();

    // ---- phase 2-pre: issue pe prefetch (hides HBM under exp phase) ----
    float sv[CHUNK];
    #pragma unroll
    for (int u = 0; u < CHUNK; ++u)
        sv[u] = (u < count) ? pe[((long)b * F + fl_f[u]) * P + tid] : 0.0f;

    // ---- phase 2: unnormalized tile weights (underflow masks the window) ----
    for (int idx = tid; idx < count * TT; idx += BLOCK) {
        const int a = idx >> 5, j = idx & (TT - 1);
        const float z = ((float)(t0 + j) - fl_tb[a]) * inv_sig;
        wt[idx] = __expf(-0.5f * z * z);
    }
    __syncthreads();

    // ---- phase 3: per-thread (p = tid) register accumulation ----
    float acc[TT];
    #pragma unroll
    for (int j = 0; j < TT; ++j) acc[j] = 0.0f;

    #pragma unroll
    for (int a = 0; a < CHUNK; ++a) {
        if (a < count) {
            const float s = sv[a] * fl_sc[a];
            const float4* w4 = (const float4*)&wt[a * TT];  // uniform -> bcast
            #pragma unroll
            for (int q = 0; q < TT / 4; ++q) {
                const float4 w = w4[q];
                acc[q*4+0] += s * w.x;
                acc[q*4+1] += s * w.y;
                acc[q*4+2] += s * w.z;
                acc[q*4+3] += s * w.w;
            }
        }
    }
    for (int a = CHUNK; a < count; ++a) {    // rare tail
        const float s = pe[((long)b * F + fl_f[a]) * P + tid] * fl_sc[a];
        const float4* w4 = (const float4*)&wt[a * TT];
        #pragma unroll
        for (int q = 0; q < TT / 4; ++q) {
            const float4 w = w4[q];
            acc[q*4+0] += s * w.x;
            acc[q*4+1] += s * w.y;
            acc[q*4+2] += s * w.z;
            acc[q*4+3] += s * w.w;
        }
    }

    // ---- phase 4: padded-LDS transpose, block-coalesced full-line writes ----
    #pragma unroll
    for (int j = 0; j < TT; ++j)
        stg[tid * (TT + 1) + j] = acc[j];    // bank (tid+j)%32: 2-way, free
    __syncthreads();

    const long rowbase = (long)b * P * T + t0;
    #pragma unroll
    for (int g = 0; g < BLOCK / 32; ++g) {
        const int p  = g * 32 + (tid >> 3);
        const int j4 = (tid & 7) * 4;
        float4 v;
        v.x = stg[p * (TT + 1) + j4 + 0];
        v.y = stg[p * (TT + 1) + j4 + 1];
        v.z = stg[p * (TT + 1) + j4 + 2];
        v.w = stg[p * (TT + 1) + j4 + 3];
        *(float4*)(out + rowbase + (long)p * T + j4) = v;
    }
}

extern "C" void kernel_launch(void* const* d_in, const int* in_sizes, int n_in,
                              void* d_out, int out_size, void* d_ws, size_t ws_size,
                              hipStream_t stream) {
    const float* pe    = (const float*)d_in[0];  // [B,F,P]
    const float* ftime = (const float*)d_in[1];  // [B,F,1]
    const float* fconf = (const float*)d_in[2];  // [B,F,1]
    const float* sigma = (const float*)d_in[4];  // scalar

    const int BF = in_sizes[1];            // B*F = 1024
    const int P  = in_sizes[0] / BF;       // 256
    const int B  = BF / F;                 // 8
    const int T  = out_size / (B * P);     // 2048
    const int ntiles = (T + TT - 1) / TT;  // 64

    flash_reco_tile<<<dim3(B * ntiles), dim3(BLOCK), 0, stream>>>(
        pe, ftime, fconf, sigma, (float*)d_out, P, T, ntiles);
}